// Round 9
// baseline (519.852 us; speedup 1.0000x reference)
//
#include <hip/hip_runtime.h>
#include <math.h>

#define BIGS  1.0e8f           // sentinel in scaled units
#define YPADV 12000.0f         // pad value: cost >= ~1.4e8 acts as BIG
#define TFULL 1024
#define TSD   1022
#define NBINS 64
#define CH    32               // diagonals per chunk (fully unrolled)
#define SQ    3.79828185f      // sqrt(1/(0.1*ln2)): cost_scaled = ((x-y)*SQ)^2
#define GAMLN2 0.069314718f    // 0.1*ln2: unscale factor

#define WS_PART  256

// ---------------- shared memory layouts (union, <64KB) ----------------
struct SmemDtw {
  float ys[1408];              // [128 front pad][1024 y][256 back pad], pre-scaled
  float bnd[8][3][32];         // per-wave chunk-indexed boundary buffers (mod 3)
};
struct SmemFused {
  float xr[1024], yr[1024];
  float fmp[5 * 1024], fmt[5 * 1024];
  float aA[512], aB[512];
  float part[2048];
  float hx[NBINS], hy[NBINS];
  float red[8];
  float energy[8];
};
union SmemU { SmemDtw d; SmemFused f; };

__device__ __forceinline__ float min3f(float a, float b, float c) {
  return fminf(fminf(a, b), c);   // clang fuses to v_min3_f32
}

// ---------------- reductions ----------------
__device__ __forceinline__ float waveReduceSum(float v) {
#pragma unroll
  for (int o = 32; o > 0; o >>= 1) v += __shfl_xor(v, o, 64);
  return v;
}

template <int OP>  // 0=sum 1=min 2=max
__device__ __forceinline__ float comb2(float a, float b) {
  if (OP == 0) return a + b;
  if (OP == 1) return fminf(a, b);
  return fmaxf(a, b);
}

template <int OP>
__device__ float blockReduce(float v, float* red, int tid) {
#pragma unroll
  for (int o = 32; o > 0; o >>= 1) v = comb2<OP>(v, __shfl_xor(v, o, 64));
  __syncthreads();
  if ((tid & 63) == 0) red[tid >> 6] = v;
  __syncthreads();
  if (tid == 0) {
    float r = red[0];
#pragma unroll
    for (int w = 1; w < 8; ++w) r = comb2<OP>(r, red[w]);
    red[0] = r;
  }
  __syncthreads();
  return red[0];
}

// ---------------- cdf_variance partial (512 threads) ----------------
__device__ float cdf_pair(const float* X, const float* Y, int N, SmemFused& s, int tid) {
  float xlo = 3.4e38f, xhi = -3.4e38f, ylo = 3.4e38f, yhi = -3.4e38f;
  for (int i = tid; i < N; i += 512) {
    float xv = X[i], yv = Y[i];
    xlo = fminf(xlo, xv); xhi = fmaxf(xhi, xv);
    ylo = fminf(ylo, yv); yhi = fmaxf(yhi, yv);
  }
  xlo = blockReduce<1>(xlo, s.red, tid);
  xhi = blockReduce<2>(xhi, s.red, tid);
  ylo = blockReduce<1>(ylo, s.red, tid);
  yhi = blockReduce<2>(yhi, s.red, tid);
  float xinv = 1.f / (xhi - xlo + 1e-6f);
  float yinv = 1.f / (yhi - ylo + 1e-6f);

  int bin = tid >> 3, sub = tid & 7;          // 64 bins x 8 sub-threads
  float c = (float)bin * (1.f / 63.f);
  float hxp = 0.f, hyp = 0.f;
  for (int i = sub; i < N; i += 8) {
    float dx = (X[i] - xlo) * xinv - c;
    float dy = (Y[i] - ylo) * yinv - c;
    hxp += __expf(-200.f * dx * dx);
    hyp += __expf(-200.f * dy * dy);
  }
  s.part[tid] = hxp;
  s.part[1024 + tid] = hyp;
  __syncthreads();
  if (tid < NBINS) {
    float hx = 1e-6f, hy = 1e-6f;
#pragma unroll
    for (int t = 0; t < 8; ++t) {
      hx += s.part[tid * 8 + t];
      hy += s.part[1024 + tid * 8 + t];
    }
    s.hx[tid] = hx; s.hy[tid] = hy;
  }
  __syncthreads();
  if (tid == 0) {
    float totx = 0.f, toty = 0.f;
    for (int b2 = 0; b2 < NBINS; ++b2) { totx += s.hx[b2]; toty += s.hy[b2]; }
    float ix = 1.f / totx, iy = 1.f / toty;
    float cx = 0.f, cy = 0.f;
    for (int b2 = 0; b2 < NBINS; ++b2) {
      cx += s.hx[b2] * ix; cy += s.hy[b2] * iy;
      s.hx[b2] = cx; s.hy[b2] = cy;
    }
  }
  __syncthreads();
  float p = 0.f;
  if (tid < NBINS) { float d = s.hx[tid] - s.hy[tid]; p = d * d; }
  return blockReduce<0>(p, s.red, tid);
}

// ---------------- db4 wavelet map (512 threads) ----------------
__device__ void wavelet_map(const float* row1024, float* fm, SmemFused& s, int tid, bool doEnergy) {
  const float LOF[8] = {-0.010597401784997278f, 0.032883011666982945f, 0.030841381835986965f,
                        -0.18703481171888114f, -0.02798376941698385f, 0.6308807679295904f,
                        0.7148465705525415f, 0.23037781330885523f};
  const float HIF[8] = {0.23037781330885523f, -0.7148465705525415f, 0.6308807679295904f,
                        0.02798376941698385f, -0.18703481171888114f, -0.030841381835986965f,
                        0.032883011666982945f, 0.010597401784997278f};
  const float* ain = row1024;
  int Lin = 1024;
  for (int lvl = 0; lvl < 5; ++lvl) {
    int Lout = Lin >> 1;                 // 512,256,128,64,32
    float* aout = (lvl & 1) ? s.aA : s.aB;
    float d = 0.f, a = 0.f;
    if (tid < Lout) {
#pragma unroll
      for (int kk = 0; kk < 8; ++kk) {
        int idx = 2 * tid + kk - 3;      // stride 2, SAME pad
        float v = (idx >= 0 && idx < Lin) ? ain[idx] : 0.f;
        d = fmaf(v, HIF[kk], d);
        a = fmaf(v, LOF[kk], a);
      }
      aout[tid] = a;
    }
    fm[lvl * 1024 + tid] = (tid < Lout) ? d : 0.f;
    fm[lvl * 1024 + tid + 512] = 0.f;
    if (doEnergy) {
      float e = (tid < Lout) ? fabsf(d) : 0.f;
      float se = blockReduce<0>(e, s.red, tid);
      if (tid == 0) s.energy[lvl] = se * (1.f / 1024.f);
    }
    __syncthreads();
    ain = aout; Lin = Lout;
  }
}

// ------------- main fused kernel: 192 blocks x 512 threads -------------
// blocks [0,128): soft-DTW (q = mode*64 + b).  [128,192): fused per-batch losses.
__global__ __launch_bounds__(512)
void mdl_main(const float* __restrict__ pred, const float* __restrict__ tgt,
              float* __restrict__ ws) {
  __shared__ SmemU sm;
  const int blk = blockIdx.x;
  const int tid = threadIdx.x;

  if (blk < 128) {
    // ===== soft-DTW: G=2, all-register recurrence (y + DP flow via DPP) =====
    SmemDtw& s = sm.d;
    const int mode = blk >> 6;          // 0: raw (T=1024), 1: 2nd deriv (T=1022)
    const int b = blk & 63;
    const int T = mode ? TSD : TFULL;
    const float* xr = pred + b * 1024;
    const float* yr = tgt + b * 1024;

    // stage y (pre-scaled) with BIG pads; init boundary buffers
    for (int i = tid; i < 1408; i += 512) {
      int j = i - 128;
      float v = YPADV;
      if (j >= 0 && j < T)
        v = (mode ? (yr[j + 2] - 2.f * yr[j + 1] + yr[j]) : yr[j]) * SQ;
      s.ys[i] = v;
    }
    for (int i = tid; i < 8 * 3 * 32; i += 512) (&s.bnd[0][0][0])[i] = BIGS;

    // x registers: thread owns rows iA=2t+1, iB=2t+2 (1-based)
    const int iA = 2 * tid + 1, iB = iA + 1;
    float xA = YPADV, xB = YPADV;
    if (iA <= T) xA = (mode ? (xr[iA + 1] - 2.f * xr[iA] + xr[iA - 1]) : xr[iA - 1]) * SQ;
    if (iB <= T) xB = (mode ? (xr[iB + 1] - 2.f * xr[iB] + xr[iB - 1]) : xr[iB - 1]) * SQ;
    __syncthreads();

    const int w = tid >> 6, lane = tid & 63, li = lane & 31;
    const int c_begin = 4 * w;
    const int c_end = (min(128 * w + 128, T) + T - 2) >> 5;
    const int M = ((min(1024, T) + T - 2) >> 5) + 8;     // 71
    const int twoT = 2 * T;
    const bool isTarget = (tid == ((T - 2) >> 1));

    float a1 = BIGS, a2 = BIGS, b1 = BIGS;               // own A@k-1, A@k-2, B@k-1
    float nprev = (w == 0 && lane == 0) ? 0.f : BIGS;    // nbr B@k-2 (R[0,0] seed)
    float ans = 0.f;

    for (int m = 0; m < M; ++m) {
      const int c = m - w;
      if (c >= c_begin && c <= c_end) {
        const int k0 = 2 + (c << 5);
        // ---- chunk-edge LDS (4 reads total; recurrence itself is LDS-free) ----
        float yA = s.ys[128 + k0 - 2 * tid - 2];          // y for cell A @ k0
        float yB = s.ys[128 + k0 - 2 * tid - 3];          // y for cell B @ k0
        float ybnd = s.ys[128 + k0 - 128 * w - 1 + li];   // lane0 y-injection stripe
        float rlane = BIGS;                               // ring stripe
        if (w > 0) {
          const int cm = c % 3, cp = (c + 2) % 3;
          const float* rb = &s.bnd[w - 1][0][0];
          rlane = rb[li ? (cm * 32 + li - 1) : (cp * 32 + 31)];
        }
        float* lring = &s.bnd[w][c % 3][0];
        // ---- 32 diagonals, pure register/DPP/VALU ----
#pragma unroll
        for (int j = 0; j < CH; ++j) {
          float rvj = __int_as_float(
              __builtin_amdgcn_readlane(__float_as_int(rlane), j));
          float ybj = __int_as_float(
              __builtin_amdgcn_readlane(__float_as_int(ybnd), j));
          // nb = neighbor's B@k-1; lane0 takes ring value (DPP old operand)
          float nb = __int_as_float(__builtin_amdgcn_update_dpp(
              __float_as_int(rvj), __float_as_int(b1),
              0x138 /*WAVE_SHR1*/, 0xF, 0xF, false));
          // cell B (row iB): deps a1, b1, a2
          float dB = xB - yB;
          float mnB = min3f(a1, b1, a2);
          float eB = exp2f(mnB - a1) + exp2f(mnB - b1) + exp2f(mnB - a2);
          float dkB = fmaf(dB, dB, mnB) - log2f(eB);
          // cell A (row iA): deps nb, a1, nprev
          float dA = xA - yA;
          float mnA = min3f(nb, a1, nprev);
          float eA = exp2f(mnA - nb) + exp2f(mnA - a1) + exp2f(mnA - nprev);
          float dkA = fmaf(dA, dA, mnA) - log2f(eA);
          if (lane == 63) lring[j] = dkB;                 // boundary for next wave
          if (k0 + j == twoT) ans = isTarget ? dkB : ans; // capture R[T,T]
          // advance state (register renaming)
          nprev = nb; a2 = a1; a1 = dkA; b1 = dkB;
          // y flows diagonally: yA(k+1) = nbr's yB(k); lane0 injected from stripe
          float yAn = __int_as_float(__builtin_amdgcn_update_dpp(
              __float_as_int(ybj), __float_as_int(yB),
              0x138 /*WAVE_SHR1*/, 0xF, 0xF, false));
          yB = yA; yA = yAn;
        }
      }
      __syncthreads();
    }
    if (isTarget) ws[blk] = ans * GAMLN2;
  } else {
    // =================== fused per-batch losses (512 threads) ===================
    SmemFused& s = sm.f;
    const int b = blk - 128;
    const float* xg = pred + b * 1024;
    const float* yg = tgt + b * 1024;
    s.xr[tid] = xg[tid];             s.yr[tid] = yg[tid];
    s.xr[tid + 512] = xg[tid + 512]; s.yr[tid + 512] = yg[tid + 512];
    __syncthreads();

    float* sdx = s.fmp;
    float* sdy = s.fmp + 1024;
    float spdacc = 0.f;
    for (int i = tid; i < TSD; i += 512) {
      float a = s.xr[i + 2] - 2.f * s.xr[i + 1] + s.xr[i];
      float cc = s.yr[i + 2] - 2.f * s.yr[i + 1] + s.yr[i];
      sdx[i] = a; sdy[i] = cc;
      spdacc += fabsf(a);
    }
    float spp = blockReduce<0>(fabsf(s.xr[tid]) + fabsf(s.xr[tid + 512]), s.red, tid);
    float spd = blockReduce<0>(spdacc, s.red, tid);

    float c1 = cdf_pair(s.xr, s.yr, 1024, s, tid);
    float c2 = cdf_pair(sdx, sdy, TSD, s, tid);

    wavelet_map(s.xr, s.fmp, s, tid, true);
    wavelet_map(s.yr, s.fmt, s, tid, false);

    __syncthreads();
    if (tid == 0) {
      float e[5] = {s.energy[0], s.energy[1], s.energy[2], s.energy[3], s.energy[4]};
      int peak = 0; float best = e[0];
#pragma unroll
      for (int l = 1; l < 5; ++l) if (e[l] > best) { best = e[l]; peak = l; }
      float tot = 0.f, sel = 0.f;
#pragma unroll
      for (int l = 0; l < 5; ++l) {
        tot += e[l];
        if (l >= peak - 2 && l <= peak + 2) sel += e[l];
      }
      s.energy[7] = 1.f - sel / (tot + 1e-6f);
    }
    __syncthreads();
    float fr = s.energy[7];

    float c3 = cdf_pair(s.fmp, s.fmt, 5120, s, tid);

    if (tid == 0) {
      float* o = ws + WS_PART + b * 8;
      o[0] = c1; o[1] = c2; o[2] = c3;
      o[3] = fr; o[4] = spp; o[5] = spd;
    }
  }
}

// ---------------- final combine: 1 block x 64 threads ----------------
__global__ void mdl_combine(const float* __restrict__ ws, float* __restrict__ out) {
  const int lane = threadIdx.x;
  float vt = ws[lane];               // dtw time partial (batch=lane)
  float vs = ws[64 + lane];          // dtw sd partial
  const float* pp = ws + WS_PART + lane * 8;
  float c1 = pp[0], c2 = pp[1], c3 = pp[2], fr = pp[3], sp = pp[4], spd = pp[5];
  vt = waveReduceSum(vt);  vs = waveReduceSum(vs);
  c1 = waveReduceSum(c1);  c2 = waveReduceSum(c2);  c3 = waveReduceSum(c3);
  fr = waveReduceSum(fr);  sp = waveReduceSum(sp);  spd = waveReduceSum(spd);
  if (lane == 0) {
    float dtw_t = vt * (1.f / 64.f);
    float dtw_s = vs * (1.f / 64.f);
    float l_time = dtw_t + sp * (1.f / 65536.f) + c1 * (1.f / 4096.f);
    float l_sd   = dtw_s + spd * (1.f / 65408.f) + c2 * (1.f / 4096.f);
    float l_freq = fr * (1.f / 64.f) + c3 * (1.f / 4096.f);
    float total = 1.5f * l_time + 0.8f * l_freq + 1.2f * l_sd;
    out[0] = total; out[1] = l_time; out[2] = l_freq; out[3] = l_sd;
  }
}

extern "C" void kernel_launch(void* const* d_in, const int* in_sizes, int n_in,
                              void* d_out, int out_size, void* d_ws, size_t ws_size,
                              hipStream_t stream) {
  const float* pred = (const float*)d_in[0];
  const float* tgt  = (const float*)d_in[1];
  float* out = (float*)d_out;
  float* ws  = (float*)d_ws;
  mdl_main<<<dim3(192), dim3(512), 0, stream>>>(pred, tgt, ws);
  mdl_combine<<<dim3(1), dim3(64), 0, stream>>>(ws, out);
}